// Round 10
// baseline (200.546 us; speedup 1.0000x reference)
//
#include <hip/hip_runtime.h>

// SGCN fused: out[n,d,t,w] = sum_v (sum_c x[n,c,t,v]*W[c,d] + b[d]) * a[n,t,v,w]
// plus exact f32 copy of a into d_out second region.
// N=64, C_IN=C_OUT=64, T=300, V=25.
//
// R10: ZERO-BARRIER wave-independent design. Each wave owns 5 whole t's,
// stages into wave-PRIVATE LDS, computes full 64-d per t, stores. No
// __syncthreads anywhere -> 12 independent memory streams per CU issue
// continuously (no phase-locked queue drains).
// Step1 swapped: y^T[v][d] = x^T[v][c] . W[c][d]; W pre-packed into
// B-fragment order in d_ws (prep kernel), hoisted out of the t-loop.
// Step2 = R3's verified swapped form (consecutive-w f32x4 stores).

typedef __attribute__((ext_vector_type(8))) short short8;
typedef __attribute__((ext_vector_type(4))) float f32x4;

#define XS_S 66
#define YS_S 36
#define AT_S 36
#define AOFF 30720000L

__device__ __forceinline__ unsigned short f2bf(float f) {
    unsigned int u = __builtin_bit_cast(unsigned int, f);
    return (unsigned short)((u + 0x7FFFu + ((u >> 16) & 1u)) >> 16);
}

// wpack[((dj*2+ki)*64+lane)*8+i] = bf16(W[c][d]), c = 32ki+8*(lane>>4)+i,
// d = 16dj+(lane&15)  -- swapped-step1 B-fragment order.
__global__ void sgcn_prep(const float* __restrict__ Wg, unsigned short* __restrict__ wp)
{
    const int tid = threadIdx.x;
#pragma unroll
    for (int m = 0; m < 16; ++m) {
        const int g  = tid + 256 * m;
        const int i  = g & 7, ln = (g >> 3) & 63, ki = (g >> 9) & 1, dj = g >> 10;
        const int c  = 32 * ki + 8 * (ln >> 4) + i;
        const int d  = 16 * dj + (ln & 15);
        wp[g] = f2bf(Wg[c * 64 + d]);
    }
}

__global__ __launch_bounds__(256, 3)
void sgcn_wave(const float* __restrict__ xg, const float* __restrict__ ag,
               const unsigned short* __restrict__ wp, const float* __restrict__ bg,
               float* __restrict__ outg)
{
    __shared__ alignas(16) unsigned short Xs[4][32 * XS_S];  // x^T [v][c], per wave
    __shared__ alignas(16) unsigned short At[4][32 * AT_S];  // a^T [w][v], per wave
    __shared__ alignas(16) unsigned short Ys[4][64 * YS_S];  // y   [d][v], per wave

    const int tid  = threadIdx.x;
    const int wid  = tid >> 6;
    const int lane = tid & 63;
    const int q    = lane >> 4;   // 0..3
    const int lo   = lane & 15;   // 0..15

    // global wave id -> 5 consecutive t's of one n (base % 300 <= 295 always)
    const int gwid = blockIdx.x * 4 + wid;
    const int base = gwid * 5;
    const int n    = base / 300;
    const int t0   = base % 300;

    unsigned short* xs = Xs[wid];
    unsigned short* at = At[wid];
    unsigned short* ys = Ys[wid];

    // ---- zero private Xs/At once (K-pads + NaN safety; Ys fully rewritten) --
    for (int e = lane; e < 32 * XS_S; e += 64) xs[e] = 0;
    for (int e = lane; e < 32 * AT_S; e += 64) at[e] = 0;

    // ---- hoisted W fragments (B-operand of swapped step1) + bias ----------
    short8 wfrag[4][2];
#pragma unroll
    for (int dj = 0; dj < 4; ++dj)
#pragma unroll
        for (int ki = 0; ki < 2; ++ki)
            wfrag[dj][ki] = *(const short8*)&wp[((dj * 2 + ki) * 64 + lane) * 8];

    f32x4 binit[4];
#pragma unroll
    for (int dj = 0; dj < 4; ++dj) {
        const float b = bg[16 * dj + lo];
        binit[dj] = f32x4{b, b, b, b};
    }

    // ---- hoisted per-lane offsets ------------------------------------------
    int xoff[25], xloff[25];
#pragma unroll
    for (int m = 0; m < 25; ++m) {
        const int f = lane + 64 * m;          // 0..1599, exact
        const int c = f / 25, v = f - 25 * c;
        xoff[m]  = c * 7500 + v;
        xloff[m] = v * XS_S + c;
    }
    int aloff[10];
#pragma unroll
    for (int m = 0; m < 10; ++m) {
        const int f = lane + 64 * m;          // valid < 625
        const int v = f / 25, w = f - 25 * v;
        aloff[m] = w * AT_S + v;
    }

    const float* xp = xg + n * 480000 + t0 * 25;
    const float* ap = ag + n * 187500 + t0 * 625;
    float*       cp = outg + AOFF + n * 187500 + t0 * 625;
    float*       op = outg + n * 480000 + t0 * 25;

    for (int s = 0; s < 5; ++s) {
        // ---- loads (coalesced dwords; wave-private, no sync needed) --------
        float xd[25];
#pragma unroll
        for (int m = 0; m < 25; ++m) xd[m] = xp[xoff[m]];
        float ad[10];
#pragma unroll
        for (int m = 0; m < 10; ++m)
            if (m < 9 || lane < 49) ad[m] = ap[lane + 64 * m];

        // ---- scatter to private LDS (+ a f32 copy-out) ---------------------
#pragma unroll
        for (int m = 0; m < 25; ++m) xs[xloff[m]] = f2bf(xd[m]);
#pragma unroll
        for (int m = 0; m < 10; ++m)
            if (m < 9 || lane < 49) {
                cp[lane + 64 * m] = ad[m];
                at[aloff[m]] = f2bf(ad[m]);
            }

        // ---- step 1 (swapped): y^T[v][d] = x^T[v][c] . W[c][d] + b ---------
        // A-frag from Xs[v][c]; B-frag = wfrag (hoisted). M=32(v pad), N=64(d), K=64.
        short8 xf[2][2];
#pragma unroll
        for (int vi = 0; vi < 2; ++vi)
#pragma unroll
            for (int ki = 0; ki < 2; ++ki)
                xf[vi][ki] = *(const short8*)&xs[(16 * vi + lo) * XS_S + 32 * ki + 8 * q];

        f32x4 accy[2][4];
#pragma unroll
        for (int vi = 0; vi < 2; ++vi)
#pragma unroll
            for (int dj = 0; dj < 4; ++dj) accy[vi][dj] = binit[dj];
#pragma unroll
        for (int ki = 0; ki < 2; ++ki)
#pragma unroll
            for (int vi = 0; vi < 2; ++vi)
#pragma unroll
                for (int dj = 0; dj < 4; ++dj)
                    accy[vi][dj] = __builtin_amdgcn_mfma_f32_16x16x32_bf16(
                        xf[vi][ki], wfrag[dj][ki], accy[vi][dj], 0, 0, 0);

        // ---- y^T (D: row=v=16vi+4q+r, col=d=16dj+lo) -> Ys[d][v] packed b64 -
#pragma unroll
        for (int vi = 0; vi < 2; ++vi)
#pragma unroll
            for (int dj = 0; dj < 4; ++dj) {
                const unsigned int p0 =
                    (unsigned int)f2bf(accy[vi][dj][0]) |
                    ((unsigned int)f2bf(accy[vi][dj][1]) << 16);
                const unsigned int p1 =
                    (unsigned int)f2bf(accy[vi][dj][2]) |
                    ((unsigned int)f2bf(accy[vi][dj][3]) << 16);
                uint2 pk; pk.x = p0; pk.y = p1;
                *(uint2*)&ys[(16 * dj + lo) * YS_S + 16 * vi + 4 * q] = pk;
            }

        // ---- step 2 (swapped): O^T[w][d] = a^T[w][v] . y[d][v] -------------
        short8 af[2];
#pragma unroll
        for (int wi = 0; wi < 2; ++wi)
            af[wi] = *(const short8*)&at[(16 * wi + lo) * AT_S + 8 * q];
        short8 yf[4];
#pragma unroll
        for (int dj = 0; dj < 4; ++dj)
            yf[dj] = *(const short8*)&ys[(16 * dj + lo) * YS_S + 8 * q];

        f32x4 acco[2][4];
#pragma unroll
        for (int wi = 0; wi < 2; ++wi)
#pragma unroll
            for (int dj = 0; dj < 4; ++dj) acco[wi][dj] = f32x4{0.f, 0.f, 0.f, 0.f};
#pragma unroll
        for (int wi = 0; wi < 2; ++wi)
#pragma unroll
            for (int dj = 0; dj < 4; ++dj)
                acco[wi][dj] = __builtin_amdgcn_mfma_f32_16x16x32_bf16(
                    af[wi], yf[dj], acco[wi][dj], 0, 0, 0);

        // ---- store out[n,d,t,w]; lane's regs = consecutive w ---------------
#pragma unroll
        for (int dj = 0; dj < 4; ++dj) {
            float* od = op + (16 * dj + lo) * 7500;
            *(f32x4*)(od + 4 * q) = acco[0][dj];            // w = 4q..4q+3
            if (q < 2)
                *(f32x4*)(od + 16 + 4 * q) = acco[1][dj];   // w = 16..23
            else if (q == 2)
                od[24] = acco[1][dj][0];                    // w = 24
        }

        xp += 25; ap += 625; cp += 625; op += 25;
    }
}

extern "C" void kernel_launch(void* const* d_in, const int* in_sizes, int n_in,
                              void* d_out, int out_size, void* d_ws, size_t ws_size,
                              hipStream_t stream) {
    const float* x = (const float*)d_in[0];
    const float* a = (const float*)d_in[1];
    const float* W = (const float*)d_in[2];
    const float* b = (const float*)d_in[3];
    float* out = (float*)d_out;
    unsigned short* wpk = (unsigned short*)d_ws;   // 4096 bf16 = 8KB

    hipLaunchKernelGGL(sgcn_prep, dim3(1), dim3(256), 0, stream, W, wpk);
    // 960 blocks x 4 waves x 5 t = 19200 (n,t) tasks, exact
    hipLaunchKernelGGL(sgcn_wave, dim3(960), dim3(256), 0, stream,
                       x, a, wpk, b, out);
}

// Round 11
// 89.121 us; speedup vs baseline: 2.2503x; 2.2503x over previous
//
#include <hip/hip_runtime.h>

// SGCN fused: out[n,d,t,w] = sum_v (sum_c x[n,c,t,v]*W[c,d] + b[d]) * a[n,t,v,w]
// plus exact f32 copy of a into d_out second region.
// N=64, C_IN=C_OUT=64, T=300, V=25.
//
// R11 = R3 (best, 76.9us) + W-prep ONLY (no swizzle):
//   W^T pre-converted to bf16 into d_ws by a 1-block prep kernel; waves build
//   wfrag with 4 direct b128 loads (L2-hit). No per-block W read/LDS staging.
// Block = 512 threads (8 waves), handles (n, t0..t0+3).
// Wave wid: tl = wid>>1 (t index), dh = wid&1 (32-row d-half).

typedef __attribute__((ext_vector_type(8))) short short8;
typedef __attribute__((ext_vector_type(4))) float f32x4;

#define XS_S 66   // Xs row stride (ushort)
#define YS_S 36   // Ys row stride
#define AT_S 36   // At row stride

__device__ __forceinline__ unsigned short f2bf(float f) {
    unsigned int u = __builtin_bit_cast(unsigned int, f);
    return (unsigned short)((u + 0x7FFFu + ((u >> 16) & 1u)) >> 16);
}

__global__ void sgcn_prep(const float* __restrict__ Wg, unsigned short* __restrict__ wt)
{
    // wt[d*64 + c] = bf16(Wg[c*64 + d]);  one block of 256 threads
    const int tid = threadIdx.x;
#pragma unroll
    for (int m = 0; m < 16; ++m) {
        const int e = tid + 256 * m;          // e = d*64 + c
        const int d = e >> 6, c = e & 63;
        wt[e] = f2bf(Wg[c * 64 + d]);
    }
}

__global__ __launch_bounds__(512, 6)
void sgcn_fused(const float* __restrict__ xg, const float* __restrict__ ag,
                const unsigned short* __restrict__ wt, const float* __restrict__ bg,
                float* __restrict__ outg)
{
    __shared__ alignas(16) unsigned short Xs[4 * 32 * XS_S];  // x [tl][v][c]
    __shared__ alignas(16) unsigned short Ys[8 * 32 * YS_S];  // y [wave][dl][v]
    __shared__ alignas(16) unsigned short At[4 * 32 * AT_S];  // a^T [tl][w][v]

    const int tid  = threadIdx.x;
    const int wid  = tid >> 6;
    const int lane = tid & 63;
    const int q    = lane >> 4;   // 0..3
    const int lo   = lane & 15;   // 0..15

    const int bid = blockIdx.x;
    const int n   = bid / 75;
    const int t0  = (bid % 75) * 4;

    // ---------------- issue all global loads (independent, early) ----------
    // x slab: 64 c-rows x 100 floats (4 t's) = 1600 float4
    f32x4 xv[4];
    const long xbase = ((long)n * 64 * 300 + t0) * 25;
#pragma unroll
    for (int m = 0; m < 4; ++m) {
        const int f = tid + 512 * m;
        if (m < 3 || f < 1600) {
            const int c = f / 25, j = f % 25;
            xv[m] = *(const f32x4*)(xg + xbase + (long)c * 7500 + 4 * j);
        }
    }
    // a slab: 2500 floats = 625 float4
    f32x4 av[2];
    const long abase = ((long)n * 300 + t0) * 625;
#pragma unroll
    for (int m = 0; m < 2; ++m) {
        const int f = tid + 512 * m;
        if (m < 1 || f < 625)
            av[m] = *(const f32x4*)(ag + abase + 4 * f);
    }

    // ---------------- per-wave W fragments from prepped wt (L2-hit) --------
    const int tl = wid >> 1;
    const int dh = wid & 1;
    const int t  = t0 + tl;
    const int d0 = 32 * dh;

    short8 wfrag[2][2];
#pragma unroll
    for (int mi = 0; mi < 2; ++mi)
#pragma unroll
        for (int ki = 0; ki < 2; ++ki)
            wfrag[mi][ki] = *(const short8*)&wt[(d0 + 16 * mi + lo) * 64 + 32 * ki + 8 * q];

    f32x4 bias[2];
#pragma unroll
    for (int mi = 0; mi < 2; ++mi)
#pragma unroll
        for (int r = 0; r < 4; ++r)
            bias[mi][r] = bg[d0 + 16 * mi + 4 * q + r];

    // ---------------- zero At pad columns v=25..31 (K-dim of step 2) -------
    if (tid < 128) {   // 4 tl * 32 w-rows
        unsigned short* ar = &At[(tid >> 5) * (32 * AT_S) + (tid & 31) * AT_S];
#pragma unroll
        for (int i = 25; i < 32; ++i) ar[i] = 0;
    }

    // ---------------- scatter to LDS (bf16) --------------------------------
    // x -> Xs[tl][v][c]
#pragma unroll
    for (int m = 0; m < 4; ++m) {
        const int f = tid + 512 * m;
        if (m < 3 || f < 1600) {
            const int c = f / 25, j = f % 25;
#pragma unroll
            for (int i = 0; i < 4; ++i) {
                const int e = 4 * j + i;          // 0..99 within the 4-t row
                const int tc = e / 25, v = e % 25;
                Xs[tc * (32 * XS_S) + v * XS_S + c] = f2bf(xv[m][i]);
            }
        }
    }
    // a -> f32 copy to out + At[tl][w][v]
    {
        float* aout = outg + 30720000L + abase;
#pragma unroll
        for (int m = 0; m < 2; ++m) {
            const int f = tid + 512 * m;
            if (m < 1 || f < 625) {
                *(f32x4*)(aout + 4 * f) = av[m];
#pragma unroll
                for (int i = 0; i < 4; ++i) {
                    const int e = 4 * f + i;       // (t,v,w) flat
                    const int tc = e / 625, r = e % 625;
                    At[tc * (32 * AT_S) + (r % 25) * AT_S + (r / 25)] = f2bf(av[m][i]);
                }
            }
        }
    }
    __syncthreads();   // staging complete

    // ---------------- step 1: y[dl,v] = b + sum_c W[c,d] x[c,v] ------------
    // (M=32, N=32pad, K=64)
    const unsigned short* xs = Xs + tl * (32 * XS_S);
    f32x4 accy[2][2];
#pragma unroll
    for (int mi = 0; mi < 2; ++mi) { accy[mi][0] = bias[mi]; accy[mi][1] = bias[mi]; }
#pragma unroll
    for (int ni = 0; ni < 2; ++ni)
#pragma unroll
        for (int ki = 0; ki < 2; ++ki) {
            const short8 bf = *(const short8*)&xs[(16 * ni + lo) * XS_S + 32 * ki + 8 * q];
#pragma unroll
            for (int mi = 0; mi < 2; ++mi)
                accy[mi][ni] = __builtin_amdgcn_mfma_f32_16x16x32_bf16(
                    wfrag[mi][ki], bf, accy[mi][ni], 0, 0, 0);
        }

    // ---------------- y -> Ys[dl][v] (bf16, pad cols -> 0); wave-private ---
    unsigned short* ys = Ys + wid * (32 * YS_S);
#pragma unroll
    for (int mi = 0; mi < 2; ++mi)
#pragma unroll
        for (int ni = 0; ni < 2; ++ni) {
            const int v = 16 * ni + lo;
            const bool ok = (v < 25);
#pragma unroll
            for (int r = 0; r < 4; ++r)
                ys[(16 * mi + 4 * q + r) * YS_S + v] =
                    ok ? f2bf(accy[mi][ni][r]) : (unsigned short)0;
        }

    // ---------------- step 2 (swapped): O^T[w,dl] = sum_v a^T[w,v] y[dl,v] -
    const unsigned short* at = At + tl * (32 * AT_S);
    short8 afr[2];
#pragma unroll
    for (int mi = 0; mi < 2; ++mi)
        afr[mi] = *(const short8*)&at[(16 * mi + lo) * AT_S + 8 * q];
    short8 yfr[2];
#pragma unroll
    for (int dj = 0; dj < 2; ++dj)
        yfr[dj] = *(const short8*)&ys[(16 * dj + lo) * YS_S + 8 * q];

    f32x4 acco[2][2];
#pragma unroll
    for (int mi = 0; mi < 2; ++mi)
#pragma unroll
        for (int dj = 0; dj < 2; ++dj)
            acco[mi][dj] = f32x4{0.f, 0.f, 0.f, 0.f};
#pragma unroll
    for (int mi = 0; mi < 2; ++mi)
#pragma unroll
        for (int dj = 0; dj < 2; ++dj)
            acco[mi][dj] = __builtin_amdgcn_mfma_f32_16x16x32_bf16(
                afr[mi], yfr[dj], acco[mi][dj], 0, 0, 0);

    // ---------------- store out[n,d,t,w]; lane's 4 regs = consecutive w ----
    float* op = outg + ((long)n * 64 * 300 + t) * 25;
#pragma unroll
    for (int dj = 0; dj < 2; ++dj) {
        const long dbase = (long)(d0 + 16 * dj + lo) * 7500;
        *(f32x4*)(op + dbase + 4 * q) = acco[0][dj];          // w = 4q..4q+3
        if (q < 2)
            *(f32x4*)(op + dbase + 16 + 4 * q) = acco[1][dj]; // w = 16..23
        else if (q == 2)
            op[dbase + 24] = acco[1][dj][0];                  // w = 24
    }
}

extern "C" void kernel_launch(void* const* d_in, const int* in_sizes, int n_in,
                              void* d_out, int out_size, void* d_ws, size_t ws_size,
                              hipStream_t stream) {
    const float* x = (const float*)d_in[0];
    const float* a = (const float*)d_in[1];
    const float* W = (const float*)d_in[2];
    const float* b = (const float*)d_in[3];
    float* out = (float*)d_out;
    unsigned short* wt = (unsigned short*)d_ws;   // 4096 bf16 = 8KB

    hipLaunchKernelGGL(sgcn_prep, dim3(1), dim3(256), 0, stream, W, wt);
    hipLaunchKernelGGL(sgcn_fused, dim3(64 * 75), dim3(512), 0, stream,
                       x, a, wt, b, out);
}